// Round 1
// baseline (1433.982 us; speedup 1.0000x reference)
//
#include <hip/hip_runtime.h>
#include <cstdint>
#include <cstddef>

// LinearAttention pipeline, MI355X round 1 (correctness-first baseline).
//
// Stages:
//   K1 prenorm      : channel LN over 384, write xn (bf16)
//   K2 gemm (fp32)  : qkv[o,p] = Wqkv[o,c] * xn[c,p]   M=1152 K=384 N=65536
//   K3 ksoftmax     : softmax over n=4096 per (b,head,d), in place on k section
//   K4 ctx          : ctx[d,e] = sum_n k[d,n] v[e,n]  (split-n + atomics)
//   K5 attout       : fused q-softmax*SCALE; out[e,n] = sum_d ctx[d,e] q[d,n]
//   K6 gemm (fp32)  : y[o,p] = Wout[o,c] * attout[c,p]  M=384 (reuses qkv buf)
//   K7 outnorm      : +bout, channel LN, * g, + xn, write fp32 d_out
//
// ws layout (bytes):
//   xn     bf16  @ 0           50,331,648
//   qkv    bf16  @ 50,331,648  150,994,944   (y reuses this region after K5)
//   ctx    fp32  @ 201,326,592   2,359,296
//   attout bf16  @ 203,685,888  50,331,648
//   total 254,017,536

#define B_    16
#define C_    384
#define HW_   4096
#define OC_   1152
#define CH_   96
#define SCALE_ 0.10206207261596577f
#define EPS_  1e-5f

static __device__ __forceinline__ float bfu2f(unsigned short u) {
  union { float f; unsigned int i; } x; x.i = ((unsigned int)u) << 16; return x.f;
}
static __device__ __forceinline__ unsigned short f2bfu(float f) {
  union { float f; unsigned int u; } x; x.f = f;
  unsigned int r = x.u + 0x7fffu + ((x.u >> 16) & 1u);
  return (unsigned short)(r >> 16);
}
static __device__ __forceinline__ float bflo(unsigned int u) {
  union { float f; unsigned int i; } x; x.i = u << 16; return x.f;
}
static __device__ __forceinline__ float bfhi(unsigned int u) {
  union { float f; unsigned int i; } x; x.i = u & 0xffff0000u; return x.f;
}

static __device__ __forceinline__ float wredmax(float v) {
  #pragma unroll
  for (int m = 32; m > 0; m >>= 1) v = fmaxf(v, __shfl_xor(v, m, 64));
  return v;
}
static __device__ __forceinline__ float wredsum(float v) {
  #pragma unroll
  for (int m = 32; m > 0; m >>= 1) v += __shfl_xor(v, m, 64);
  return v;
}

// ---------------- K1: prenorm ----------------
__global__ __launch_bounds__(256) void k_prenorm(const float* __restrict__ x,
                                                 const float* __restrict__ g,
                                                 unsigned short* __restrict__ xn) {
  __shared__ float gs[C_];
  int tid = threadIdx.x;
  for (int c = tid; c < C_; c += 256) gs[c] = g[c];
  __syncthreads();
  int p = blockIdx.x * 256 + tid;
  int b = p >> 12, pix = p & 4095;
  const float* xb = x + (size_t)b * C_ * HW_ + pix;
  float sum = 0.f, sq = 0.f;
  for (int c = 0; c < C_; ++c) { float v = xb[(size_t)c * HW_]; sum += v; sq += v * v; }
  float mean = sum * (1.f / C_);
  float var = sq * (1.f / C_) - mean * mean;
  float rs = rsqrtf(var + EPS_);
  unsigned short* ob = xn + (size_t)b * C_ * HW_ + pix;
  for (int c = 0; c < C_; ++c) {
    float v = (xb[(size_t)c * HW_] - mean) * rs * gs[c];
    ob[(size_t)c * HW_] = f2bfu(v);
  }
}

// ---------------- K2/K6: fp32 GEMM  dst[b,o,p] = sum_c W[o,c]*src[b,c,p] ---
// BM=128 (o) x BN=128 (p) x BK=16, 256 threads, 8x8 microtile.
// Grid swizzle: same-pixel-tile blocks -> same XCD slot for L2 reuse of src.
__global__ __launch_bounds__(256) void k_gemm(const float* __restrict__ W,
                                              const unsigned short* __restrict__ src,
                                              unsigned short* __restrict__ dst,
                                              int M, int MT) {
  __shared__ float As[16][132];
  __shared__ float Bs[16][132];
  int i = blockIdx.x;
  int xcd = i & 7, j = i >> 3;
  int ot = j % MT, ptl = j / MT;
  int ptile = ptl * 8 + xcd;           // 0..511
  int o0 = ot * 128;
  int p0 = ptile * 128;
  int b = p0 >> 12, pix0 = p0 & 4095;
  int tid = threadIdx.x;
  int tn = tid & 15, to = tid >> 4;
  const unsigned short* sb = src + (size_t)b * C_ * HW_ + pix0;

  float acc[8][8];
  #pragma unroll
  for (int a = 0; a < 8; ++a)
    #pragma unroll
    for (int q = 0; q < 8; ++q) acc[a][q] = 0.f;

  int ao = tid >> 1, ac = (tid & 1) * 8;     // A loader: o row, 8 c
  int bc = tid >> 4, bp = (tid & 15) * 8;    // B loader: c row, 8 p

  for (int k0 = 0; k0 < C_; k0 += 16) {
    const float* wp = W + (size_t)(o0 + ao) * C_ + k0 + ac;
    float4 w0 = *(const float4*)wp;
    float4 w1 = *(const float4*)(wp + 4);
    uint4 raw = *(const uint4*)(sb + (size_t)(k0 + bc) * HW_ + bp);
    As[ac + 0][ao] = w0.x; As[ac + 1][ao] = w0.y; As[ac + 2][ao] = w0.z; As[ac + 3][ao] = w0.w;
    As[ac + 4][ao] = w1.x; As[ac + 5][ao] = w1.y; As[ac + 6][ao] = w1.z; As[ac + 7][ao] = w1.w;
    Bs[bc][bp + 0] = bflo(raw.x); Bs[bc][bp + 1] = bfhi(raw.x);
    Bs[bc][bp + 2] = bflo(raw.y); Bs[bc][bp + 3] = bfhi(raw.y);
    Bs[bc][bp + 4] = bflo(raw.z); Bs[bc][bp + 5] = bfhi(raw.z);
    Bs[bc][bp + 6] = bflo(raw.w); Bs[bc][bp + 7] = bfhi(raw.w);
    __syncthreads();
    #pragma unroll
    for (int kk = 0; kk < 16; ++kk) {
      float a[8], bb[8];
      *(float4*)&a[0]  = *(const float4*)&As[kk][to * 8];
      *(float4*)&a[4]  = *(const float4*)&As[kk][to * 8 + 4];
      *(float4*)&bb[0] = *(const float4*)&Bs[kk][tn * 8];
      *(float4*)&bb[4] = *(const float4*)&Bs[kk][tn * 8 + 4];
      #pragma unroll
      for (int ii = 0; ii < 8; ++ii)
        #pragma unroll
        for (int jj = 0; jj < 8; ++jj)
          acc[ii][jj] += a[ii] * bb[jj];
    }
    __syncthreads();
  }
  #pragma unroll
  for (int ii = 0; ii < 8; ++ii) {
    int o = o0 + to * 8 + ii;
    alignas(16) unsigned short buf[8];
    #pragma unroll
    for (int jj = 0; jj < 8; ++jj) buf[jj] = f2bfu(acc[ii][jj]);
    *(uint4*)(dst + ((size_t)b * M + o) * HW_ + pix0 + tn * 8) = *(const uint4*)buf;
  }
}

// ---------------- K3: k softmax over n=4096, in place --------------------
__global__ __launch_bounds__(256) void k_ksoftmax(unsigned short* __restrict__ qkv) {
  __shared__ float red[4];
  int row = blockIdx.x;                 // 0..6143
  int b = row / 384, rem = row % 384;   // rem = h*96 + d
  unsigned short* kp = qkv + ((size_t)b * OC_ + 384 + rem) * HW_;
  int tid = threadIdx.x;
  float v[16];
  float m = -1e30f;
  #pragma unroll
  for (int it = 0; it < 16; ++it) { v[it] = bfu2f(kp[tid + it * 256]); m = fmaxf(m, v[it]); }
  m = wredmax(m);
  if ((tid & 63) == 0) red[tid >> 6] = m;
  __syncthreads();
  m = fmaxf(fmaxf(red[0], red[1]), fmaxf(red[2], red[3]));
  __syncthreads();
  float s = 0.f;
  #pragma unroll
  for (int it = 0; it < 16; ++it) { v[it] = __expf(v[it] - m); s += v[it]; }
  s = wredsum(s);
  if ((tid & 63) == 0) red[tid >> 6] = s;
  __syncthreads();
  s = red[0] + red[1] + red[2] + red[3];
  float inv = 1.f / s;
  #pragma unroll
  for (int it = 0; it < 16; ++it) kp[tid + it * 256] = f2bfu(v[it] * inv);
}

// ---------------- K4: ctx[d,e] = sum_n k[d,n] v[e,n] ---------------------
// grid (64 bh, 8 n-chunks of 512). 256 thr = 16x16, 6x6 accum each. atomics.
__global__ __launch_bounds__(256) void k_ctx(const unsigned short* __restrict__ qkv,
                                             float* __restrict__ ctx) {
  __shared__ float kT[32][98];
  __shared__ float vT[32][98];
  int bh = blockIdx.x;
  int b = bh >> 2, h = bh & 3;
  int nc = blockIdx.y;
  int tid = threadIdx.x;
  int td = tid & 15, te = tid >> 4;
  const unsigned short* kbase = qkv + ((size_t)b * OC_ + 384 + h * CH_) * HW_;
  const unsigned short* vbase = qkv + ((size_t)b * OC_ + 768 + h * CH_) * HW_;
  float acc[6][6];
  #pragma unroll
  for (int a = 0; a < 6; ++a)
    #pragma unroll
    for (int q = 0; q < 6; ++q) acc[a][q] = 0.f;

  for (int st = 0; st < 16; ++st) {
    int n0 = nc * 512 + st * 32;
    for (int e = tid; e < CH_ * 32; e += 256) {
      int d = e >> 5, n = e & 31;
      kT[n][d] = bfu2f(kbase[(size_t)d * HW_ + n0 + n]);
      vT[n][d] = bfu2f(vbase[(size_t)d * HW_ + n0 + n]);
    }
    __syncthreads();
    #pragma unroll 4
    for (int nn = 0; nn < 32; ++nn) {
      float kk[6], vv[6];
      #pragma unroll
      for (int q = 0; q < 6; ++q) kk[q] = kT[nn][td * 6 + q];
      #pragma unroll
      for (int q = 0; q < 6; ++q) vv[q] = vT[nn][te * 6 + q];
      #pragma unroll
      for (int iq = 0; iq < 6; ++iq)
        #pragma unroll
        for (int jq = 0; jq < 6; ++jq) acc[iq][jq] += kk[iq] * vv[jq];
    }
    __syncthreads();
  }
  float* cb = ctx + (size_t)bh * CH_ * CH_;
  #pragma unroll
  for (int iq = 0; iq < 6; ++iq)
    #pragma unroll
    for (int jq = 0; jq < 6; ++jq)
      atomicAdd(&cb[(size_t)(td * 6 + iq) * CH_ + te * 6 + jq], acc[iq][jq]);
}

// ---------------- K5: fused q-softmax + out[e,n] = sum_d ctx[d,e] q[d,n] --
__global__ __launch_bounds__(256) void k_attout(const unsigned short* __restrict__ qkv,
                                                const float* __restrict__ ctx,
                                                unsigned short* __restrict__ attout) {
  __shared__ float cs[CH_ * CH_];
  int bh = blockIdx.y;
  int b = bh >> 2, h = bh & 3;
  int tid = threadIdx.x;
  const float* cb = ctx + (size_t)bh * CH_ * CH_;
  for (int e = tid; e < CH_ * CH_; e += 256) cs[e] = cb[e];
  __syncthreads();
  int n = blockIdx.x * 256 + tid;
  const unsigned short* qp = qkv + ((size_t)b * OC_ + h * CH_) * HW_ + n;
  float qv[CH_];
  #pragma unroll
  for (int d = 0; d < CH_; ++d) qv[d] = bfu2f(qp[(size_t)d * HW_]);
  float m = -1e30f;
  #pragma unroll
  for (int d = 0; d < CH_; ++d) m = fmaxf(m, qv[d]);
  float s = 0.f;
  #pragma unroll
  for (int d = 0; d < CH_; ++d) { qv[d] = __expf(qv[d] - m); s += qv[d]; }
  float sc = SCALE_ / s;
  #pragma unroll
  for (int d = 0; d < CH_; ++d) qv[d] *= sc;
  unsigned short* ob = attout + ((size_t)b * C_ + h * CH_) * HW_ + n;
  #pragma unroll 1
  for (int e0 = 0; e0 < CH_; e0 += 8) {
    float acc[8];
    #pragma unroll
    for (int jj = 0; jj < 8; ++jj) acc[jj] = 0.f;
    #pragma unroll
    for (int d = 0; d < CH_; ++d) {
      float qd = qv[d];
      float4 c0 = *(const float4*)&cs[d * CH_ + e0];
      float4 c1 = *(const float4*)&cs[d * CH_ + e0 + 4];
      acc[0] += qd * c0.x; acc[1] += qd * c0.y; acc[2] += qd * c0.z; acc[3] += qd * c0.w;
      acc[4] += qd * c1.x; acc[5] += qd * c1.y; acc[6] += qd * c1.z; acc[7] += qd * c1.w;
    }
    #pragma unroll
    for (int jj = 0; jj < 8; ++jj) ob[(size_t)(e0 + jj) * HW_] = f2bfu(acc[jj]);
  }
}

// ---------------- K7: +bias, channel LN, *g, +xn, write fp32 --------------
__global__ __launch_bounds__(256) void k_outnorm(const unsigned short* __restrict__ y,
                                                 const unsigned short* __restrict__ xn,
                                                 const float* __restrict__ bout,
                                                 const float* __restrict__ g,
                                                 float* __restrict__ out) {
  __shared__ float bs[C_], gs[C_];
  int tid = threadIdx.x;
  for (int c = tid; c < C_; c += 256) { bs[c] = bout[c]; gs[c] = g[c]; }
  __syncthreads();
  int p = blockIdx.x * 256 + tid;
  int b = p >> 12, pix = p & 4095;
  const unsigned short* yb = y + (size_t)b * C_ * HW_ + pix;
  const unsigned short* xb = xn + (size_t)b * C_ * HW_ + pix;
  float sum = 0.f, sq = 0.f;
  for (int c = 0; c < C_; ++c) {
    float v = bfu2f(yb[(size_t)c * HW_]) + bs[c];
    sum += v; sq += v * v;
  }
  float mean = sum * (1.f / C_);
  float var = sq * (1.f / C_) - mean * mean;
  float rs = rsqrtf(var + EPS_);
  float* ob = out + (size_t)b * C_ * HW_ + pix;
  for (int c = 0; c < C_; ++c) {
    float v = bfu2f(yb[(size_t)c * HW_]) + bs[c];
    ob[(size_t)c * HW_] = (v - mean) * rs * gs[c] + bfu2f(xb[(size_t)c * HW_]);
  }
}

extern "C" void kernel_launch(void* const* d_in, const int* in_sizes, int n_in,
                              void* d_out, int out_size, void* d_ws, size_t ws_size,
                              hipStream_t stream) {
  const float* x    = (const float*)d_in[0];
  const float* pg   = (const float*)d_in[1];
  const float* wqkv = (const float*)d_in[2];
  const float* wout = (const float*)d_in[3];
  const float* bout = (const float*)d_in[4];
  const float* og   = (const float*)d_in[5];

  char* ws = (char*)d_ws;
  unsigned short* xn     = (unsigned short*)(ws);                  // 50,331,648 B
  unsigned short* qkv    = (unsigned short*)(ws + 50331648);       // 150,994,944 B
  float*          ctx    = (float*)(ws + 201326592);               // 2,359,296 B
  unsigned short* attout = (unsigned short*)(ws + 203685888);      // 50,331,648 B
  unsigned short* y      = qkv;  // reuse qkv region after K5
  float* out = (float*)d_out;

  k_prenorm<<<256, 256, 0, stream>>>(x, pg, xn);
  k_gemm<<<4608, 256, 0, stream>>>(wqkv, xn, qkv, OC_, 9);
  k_ksoftmax<<<6144, 256, 0, stream>>>(qkv);
  hipMemsetAsync(ctx, 0, 2359296, stream);
  k_ctx<<<dim3(64, 8), 256, 0, stream>>>(qkv, ctx);
  k_attout<<<dim3(16, 64), 256, 0, stream>>>(qkv, ctx, attout);
  k_gemm<<<1536, 256, 0, stream>>>(wout, attout, y, C_, 3);
  k_outnorm<<<256, 256, 0, stream>>>(y, xn, bout, og, out);
}

// Round 2
// 658.143 us; speedup vs baseline: 2.1788x; 2.1788x over previous
//
#include <hip/hip_runtime.h>
#include <cstdint>
#include <cstddef>

// LinearAttention MI355X round 2: pixel-major layout + bf16 MFMA GEMMs.
//
// Layouts (P = 65536 global pixels = b*4096+pix):
//   xn     bf16 [P][384]          (pixel-major prenorm output)
//   qkv    bf16 [12][P][96]       head-blocks: hb = (section*4 + h), section q=0,k=1,v=2
//   attout bf16 [P][384]
//   y      bf16 [P][384]          (reuses qkv bytes [0, 50MB) = q section, dead after K5)
//   ctx    fp32 [64][96][96]      (+ zbuf fp32 [64][96])
//   wbf    bf16 Wqkv(1152x384) then Wout(384x384)
//
// ws offsets (bytes):
//   xn @ 0                 50,331,648
//   qkv @ 50,331,648      150,994,944
//   attout @ 201,326,592   50,331,648
//   ctx @ 251,658,240       2,359,296
//   zbuf @ 254,017,536         24,576
//   wbf @ 254,042,112       1,179,648   (total 255,221,760)

#define P_     65536
#define P96_   6291456      // P_ * 96
#define ROW_   384
#define SCALE_ 0.10206207261596577f
#define EPS_   1e-5f

typedef unsigned short us16;
typedef __attribute__((ext_vector_type(8))) unsigned short ushort8;
typedef __attribute__((ext_vector_type(8))) short short8;
typedef __attribute__((ext_vector_type(4))) float f32x4;

static __device__ __forceinline__ float bfu2f(us16 u) {
  union { float f; unsigned int i; } x; x.i = ((unsigned int)u) << 16; return x.f;
}
static __device__ __forceinline__ us16 f2bfu(float f) {
  union { float f; unsigned int u; } x; x.f = f;
  unsigned int r = x.u + 0x7fffu + ((x.u >> 16) & 1u);
  return (us16)(r >> 16);
}

#define GLDS16(gp, lp) \
  __builtin_amdgcn_global_load_lds((const __attribute__((address_space(1))) void*)(gp), \
                                   (__attribute__((address_space(3))) void*)(lp), 16, 0, 0)

// ---------------- W fp32 -> bf16 ----------------
__global__ __launch_bounds__(256) void k_wcvt(const float* __restrict__ wqkv,
                                              const float* __restrict__ wout,
                                              us16* __restrict__ wbf) {
  int i = (blockIdx.x * 256 + threadIdx.x) * 4;
  const float* s = (i < 442368) ? (wqkv + i) : (wout + (i - 442368));
  wbf[i + 0] = f2bfu(s[0]); wbf[i + 1] = f2bfu(s[1]);
  wbf[i + 2] = f2bfu(s[2]); wbf[i + 3] = f2bfu(s[3]);
}

// ---------------- K1: prenorm (x channel-major fp32 -> xn pixel-major bf16)
// 64 pixels/block; thread (q=t>>6, pb=t&63) holds 96 channels of pixel pb.
__global__ __launch_bounds__(256) void k_prenorm(const float* __restrict__ x,
                                                 const float* __restrict__ g,
                                                 us16* __restrict__ xn) {
  __shared__ float gs[384];
  __shared__ float sm[4][64], sq[4][64];
  int t = threadIdx.x;
  for (int c = t; c < 384; c += 256) gs[c] = g[c];
  int qd = t >> 6, pb = t & 63;
  int p = blockIdx.x * 64 + pb;
  int b = p >> 12, pix = p & 4095;
  const float* xb = x + (size_t)b * 1572864 + pix;
  float xv[96];
  float s1 = 0.f, s2 = 0.f;
  #pragma unroll
  for (int i = 0; i < 96; ++i) {
    float v = xb[(size_t)(qd * 96 + i) * 4096];
    xv[i] = v; s1 += v; s2 += v * v;
  }
  sm[qd][pb] = s1; sq[qd][pb] = s2;
  __syncthreads();
  float su = sm[0][pb] + sm[1][pb] + sm[2][pb] + sm[3][pb];
  float ss = sq[0][pb] + sq[1][pb] + sq[2][pb] + sq[3][pb];
  float mean = su * (1.f / 384);
  float var = ss * (1.f / 384) - mean * mean;
  float rs = rsqrtf(var + EPS_);
  us16* ob = xn + (size_t)p * ROW_ + qd * 96;
  #pragma unroll
  for (int c8 = 0; c8 < 12; ++c8) {
    ushort8 u;
    #pragma unroll
    for (int j = 0; j < 8; ++j)
      u[j] = f2bfu((xv[c8 * 8 + j] - mean) * rs * gs[qd * 96 + c8 * 8 + j]);
    *(ushort8*)(ob + c8 * 8) = u;
  }
}

// ---------------- MFMA GEMM: dst[p][o] = sum_c src[p][c] * W[o][c] --------
// BM=128(p) x BN=128(o) x BK=32, 256 thr = 4 waves (2x2), 16x16x32 bf16 MFMA.
// mode 0: dst = qkv head-split  addr = (o/96)*P96 + p*96 + o%96
// mode 1: dst = y [P][384]      addr = p*384 + o
__global__ __launch_bounds__(256) void k_gemm(const us16* __restrict__ src,
                                              const us16* __restrict__ W,
                                              us16* __restrict__ dst,
                                              int MT, int mode) {
  __shared__ __align__(16) us16 As[128 * 32];
  __shared__ __align__(16) us16 Bs[128 * 32];
  int i = blockIdx.x;
  int xcd = i & 7, idx = i >> 3;
  int ot = idx % MT;
  int pt = (idx / MT) * 8 + xcd;
  int p0 = pt * 128, o0 = ot * 128;
  int tid = threadIdx.x;
  int wv = tid >> 6, l = tid & 63;
  int wr = wv >> 1, wc = wv & 1;
  int lm = l & 15, kq = l >> 4;

  f32x4 acc[4][4];
  #pragma unroll
  for (int a = 0; a < 4; ++a)
    #pragma unroll
    for (int q = 0; q < 4; ++q) acc[a][q] = (f32x4)0.f;

  int lrow = l >> 2, lcol = (l & 3) * 8;   // staging: 4 lanes per 64B row

  for (int k0 = 0; k0 < 384; k0 += 32) {
    #pragma unroll
    for (int c = 0; c < 2; ++c) {
      int ra = wv * 32 + c * 16;
      GLDS16(src + (size_t)(p0 + ra + lrow) * ROW_ + k0 + lcol, &As[ra * 32]);
      GLDS16(W   + (size_t)(o0 + ra + lrow) * ROW_ + k0 + lcol, &Bs[ra * 32]);
    }
    __syncthreads();
    const short8* A8 = (const short8*)As;
    const short8* B8 = (const short8*)Bs;
    short8 af[4], bf[4];
    #pragma unroll
    for (int ii = 0; ii < 4; ++ii) af[ii] = A8[(wr * 64 + ii * 16 + lm) * 4 + kq];
    #pragma unroll
    for (int jj = 0; jj < 4; ++jj) bf[jj] = B8[(wc * 64 + jj * 16 + lm) * 4 + kq];
    #pragma unroll
    for (int ii = 0; ii < 4; ++ii)
      #pragma unroll
      for (int jj = 0; jj < 4; ++jj)
        acc[ii][jj] = __builtin_amdgcn_mfma_f32_16x16x32_bf16(af[ii], bf[jj], acc[ii][jj], 0, 0, 0);
    __syncthreads();
  }

  // epilogue: C/D layout col=o=lane&15, row=p=(lane>>4)*4+reg (m89/m91-verified)
  #pragma unroll
  for (int ii = 0; ii < 4; ++ii) {
    int prow = p0 + wr * 64 + ii * 16 + kq * 4;
    #pragma unroll
    for (int jj = 0; jj < 4; ++jj) {
      int o = o0 + wc * 64 + jj * 16 + lm;
      f32x4 v = acc[ii][jj];
      #pragma unroll
      for (int r = 0; r < 4; ++r) {
        int p = prow + r;
        size_t addr = mode ? ((size_t)p * ROW_ + o)
                           : ((size_t)(o / 96) * P96_ + (size_t)p * 96 + (o % 96));
        dst[addr] = f2bfu(v[r]);
      }
    }
  }
}

// ---------------- K4: ctxU[d][e] = sum_p exp(k[p,d]) v[p,e]; Z_d alongside
__global__ __launch_bounds__(256) void k_ctx(const us16* __restrict__ qkv,
                                             float* __restrict__ ctx,
                                             float* __restrict__ zbuf) {
  __shared__ float kT[32][96];
  __shared__ float vT[32][96];
  int bh = blockIdx.x, b = bh >> 2, h = bh & 3;
  const us16* kb = qkv + (size_t)(4 + h) * P96_;
  const us16* vb = qkv + (size_t)(8 + h) * P96_;
  int p0 = b * 4096 + blockIdx.y * 512;
  int t = threadIdx.x;
  int td = t & 15, te = t >> 4;
  float acc[6][6];
  #pragma unroll
  for (int a = 0; a < 6; ++a)
    #pragma unroll
    for (int q = 0; q < 6; ++q) acc[a][q] = 0.f;
  float zac = 0.f;

  for (int st = 0; st < 16; ++st) {
    int pbase = p0 + st * 32;
    for (int ch = t; ch < 384; ch += 256) {
      int r = ch / 12, c8 = ch - r * 12;
      ushort8 uk = *(const ushort8*)(kb + (size_t)(pbase + r) * 96 + c8 * 8);
      ushort8 uv = *(const ushort8*)(vb + (size_t)(pbase + r) * 96 + c8 * 8);
      f32x4 k0, k1, v0, v1;
      #pragma unroll
      for (int j = 0; j < 4; ++j) {
        k0[j] = __expf(bfu2f(uk[j])); k1[j] = __expf(bfu2f(uk[j + 4]));
        v0[j] = bfu2f(uv[j]);         v1[j] = bfu2f(uv[j + 4]);
      }
      *(f32x4*)&kT[r][c8 * 8] = k0; *(f32x4*)&kT[r][c8 * 8 + 4] = k1;
      *(f32x4*)&vT[r][c8 * 8] = v0; *(f32x4*)&vT[r][c8 * 8 + 4] = v1;
    }
    __syncthreads();
    #pragma unroll 4
    for (int p = 0; p < 32; ++p) {
      float kk[6], vv[6];
      #pragma unroll
      for (int q = 0; q < 6; ++q) kk[q] = kT[p][td * 6 + q];
      #pragma unroll
      for (int q = 0; q < 6; ++q) vv[q] = vT[p][te * 6 + q];
      #pragma unroll
      for (int iq = 0; iq < 6; ++iq)
        #pragma unroll
        for (int jq = 0; jq < 6; ++jq) acc[iq][jq] += kk[iq] * vv[jq];
    }
    if (t < 96) {
      #pragma unroll 8
      for (int p = 0; p < 32; ++p) zac += kT[p][t];
    }
    __syncthreads();
  }
  float* cb = ctx + (size_t)bh * 9216;
  #pragma unroll
  for (int iq = 0; iq < 6; ++iq)
    #pragma unroll
    for (int jq = 0; jq < 6; ++jq)
      atomicAdd(&cb[(size_t)(td * 6 + iq) * 96 + te * 6 + jq], acc[iq][jq]);
  if (t < 96) atomicAdd(&zbuf[bh * 96 + t], zac);
}

// ---------------- K5: q-softmax*SCALE/Z, out[p][e] = sum_d qv[d]*ctx[d][e]
__global__ __launch_bounds__(256) void k_attout(const us16* __restrict__ qkv,
                                                const float* __restrict__ ctx,
                                                const float* __restrict__ zbuf,
                                                us16* __restrict__ attout) {
  __shared__ float cs[9216];
  __shared__ float zrs[96];
  int bh = blockIdx.y, b = bh >> 2, h = bh & 3;
  int t = threadIdx.x;
  const float* cb = ctx + (size_t)bh * 9216;
  for (int i = t; i < 9216; i += 256) cs[i] = cb[i];
  if (t < 96) zrs[t] = 1.0f / zbuf[bh * 96 + t];
  __syncthreads();
  int p = b * 4096 + blockIdx.x * 256 + t;
  const us16* qrow = qkv + (size_t)h * P96_ + (size_t)p * 96;
  float qv[96];
  #pragma unroll
  for (int c8 = 0; c8 < 12; ++c8) {
    ushort8 u = *(const ushort8*)(qrow + c8 * 8);
    #pragma unroll
    for (int j = 0; j < 8; ++j) qv[c8 * 8 + j] = bfu2f(u[j]);
  }
  float m = -1e30f;
  #pragma unroll
  for (int d = 0; d < 96; ++d) m = fmaxf(m, qv[d]);
  float s = 0.f;
  #pragma unroll
  for (int d = 0; d < 96; ++d) { qv[d] = __expf(qv[d] - m); s += qv[d]; }
  float sc = SCALE_ / s;
  #pragma unroll
  for (int d = 0; d < 96; ++d) qv[d] *= sc * zrs[d];
  us16* ob = attout + (size_t)p * ROW_ + h * 96;
  #pragma unroll 1
  for (int e0 = 0; e0 < 96; e0 += 8) {
    float a0 = 0, a1 = 0, a2 = 0, a3 = 0, a4 = 0, a5 = 0, a6 = 0, a7 = 0;
    #pragma unroll
    for (int d = 0; d < 96; ++d) {
      float qd = qv[d];
      f32x4 c0 = *(const f32x4*)&cs[d * 96 + e0];
      f32x4 c1 = *(const f32x4*)&cs[d * 96 + e0 + 4];
      a0 += qd * c0[0]; a1 += qd * c0[1]; a2 += qd * c0[2]; a3 += qd * c0[3];
      a4 += qd * c1[0]; a5 += qd * c1[1]; a6 += qd * c1[2]; a7 += qd * c1[3];
    }
    ushort8 u;
    u[0] = f2bfu(a0); u[1] = f2bfu(a1); u[2] = f2bfu(a2); u[3] = f2bfu(a3);
    u[4] = f2bfu(a4); u[5] = f2bfu(a5); u[6] = f2bfu(a6); u[7] = f2bfu(a7);
    *(ushort8*)(ob + e0) = u;
  }
}

// ---------------- K7: +bias, channel LN, *g, +xn, write channel-major fp32
__global__ __launch_bounds__(256) void k_outnorm(const us16* __restrict__ y,
                                                 const us16* __restrict__ xn,
                                                 const float* __restrict__ bout,
                                                 const float* __restrict__ g,
                                                 float* __restrict__ out) {
  __shared__ float bs[384], gs[384];
  int t = threadIdx.x;
  for (int c = t; c < 384; c += 256) { bs[c] = bout[c]; gs[c] = g[c]; }
  __syncthreads();
  int p = blockIdx.x * 256 + t;
  int b = p >> 12, pix = p & 4095;
  const us16* yb = y + (size_t)p * ROW_;
  const us16* xb = xn + (size_t)p * ROW_;
  float sum = 0.f, sq = 0.f;
  #pragma unroll 4
  for (int c8 = 0; c8 < 48; ++c8) {
    ushort8 u = *(const ushort8*)(yb + c8 * 8);
    #pragma unroll
    for (int j = 0; j < 8; ++j) {
      float v = bfu2f(u[j]) + bs[c8 * 8 + j];
      sum += v; sq += v * v;
    }
  }
  float mean = sum * (1.f / 384);
  float var = sq * (1.f / 384) - mean * mean;
  float rs = rsqrtf(var + EPS_);
  float* oB = out + (size_t)b * 1572864 + pix;
  #pragma unroll 2
  for (int c8 = 0; c8 < 48; ++c8) {
    ushort8 u = *(const ushort8*)(yb + c8 * 8);
    ushort8 ux = *(const ushort8*)(xb + c8 * 8);
    #pragma unroll
    for (int j = 0; j < 8; ++j) {
      int c = c8 * 8 + j;
      float v = bfu2f(u[j]) + bs[c];
      oB[(size_t)c * 4096] = (v - mean) * rs * gs[c] + bfu2f(ux[j]);
    }
  }
}

extern "C" void kernel_launch(void* const* d_in, const int* in_sizes, int n_in,
                              void* d_out, int out_size, void* d_ws, size_t ws_size,
                              hipStream_t stream) {
  const float* x    = (const float*)d_in[0];
  const float* pg   = (const float*)d_in[1];
  const float* wqkv = (const float*)d_in[2];
  const float* wout = (const float*)d_in[3];
  const float* bout = (const float*)d_in[4];
  const float* og   = (const float*)d_in[5];

  char* ws = (char*)d_ws;
  us16*  xn     = (us16*)(ws);
  us16*  qkv    = (us16*)(ws + 50331648);
  us16*  attout = (us16*)(ws + 201326592);
  float* ctx    = (float*)(ws + 251658240);
  float* zbuf   = (float*)(ws + 254017536);
  us16*  wbf    = (us16*)(ws + 254042112);
  us16*  y      = qkv;                 // q section reused after K5
  float* out    = (float*)d_out;

  k_wcvt<<<576, 256, 0, stream>>>(wqkv, wout, wbf);
  k_prenorm<<<1024, 256, 0, stream>>>(x, pg, xn);
  k_gemm<<<4608, 256, 0, stream>>>(xn, wbf, qkv, 9, 0);
  hipMemsetAsync(ctx, 0, 2383872, stream);       // ctx + zbuf
  k_ctx<<<dim3(64, 8), 256, 0, stream>>>(qkv, ctx, zbuf);
  k_attout<<<dim3(16, 64), 256, 0, stream>>>(qkv, ctx, zbuf, attout);
  k_gemm<<<1536, 256, 0, stream>>>(attout, wbf + 442368, y, 3, 1);
  k_outnorm<<<256, 256, 0, stream>>>(y, xn, bout, og, out);
}

// Round 3
// 501.833 us; speedup vs baseline: 2.8575x; 1.3115x over previous
//
#include <hip/hip_runtime.h>
#include <cstdint>
#include <cstddef>

// LinearAttention MI355X round 3: MFMA ctx kernel + transposed exp(k)/v layout.
//
// Layouts (P = 65536 global pixels = b*4096+pix):
//   xn     bf16 [P][384]
//   qkv    bf16: q [4][P][96] ; ekT [4][96][P] (holds exp(k)) ; vT [4][96][P]
//          (section s = o/96: 0..3 q, 4..7 ekT, 8..11 vT; all within one buffer)
//   attout bf16 [P][384]
//   y      bf16 [P][384]  (reuses qkv q-section bytes, dead after k_attout)
//   ctxs   fp32 [8][64][96][96] + zs fp32 [8][64][96]   -> scratch in d_out!
//   ctxred fp32 [64][96][96], zred fp32 [64][96]        -> ws (old ctx region)
//   wbf    bf16 Wqkv(1152x384) then Wout(384x384)
//
// ws offsets (bytes): xn @0 (50,331,648) | qkv @50,331,648 (150,994,944)
//   attout @201,326,592 (50,331,648) | ctxred @251,658,240 (2,359,296)
//   zred @254,017,536 (24,576) | wbf @254,042,112 (1,179,648) -> total 255,221,760

#define P_     65536
#define P96_   6291456
#define ROW_   384
#define NS_    8            // ctx pixel splits per (b,h)
#define CHK_   512          // 4096 / NS_
#define SCALE_ 0.10206207261596577f
#define EPS_   1e-5f

typedef unsigned short us16;
typedef __attribute__((ext_vector_type(8))) unsigned short ushort8;
typedef __attribute__((ext_vector_type(8))) short short8;
typedef __attribute__((ext_vector_type(4))) float f32x4;

static __device__ __forceinline__ float bfu2f(us16 u) {
  union { float f; unsigned int i; } x; x.i = ((unsigned int)u) << 16; return x.f;
}
static __device__ __forceinline__ us16 f2bfu(float f) {
  union { float f; unsigned int u; } x; x.f = f;
  unsigned int r = x.u + 0x7fffu + ((x.u >> 16) & 1u);
  return (us16)(r >> 16);
}

#define GLDS16(gp, lp) \
  __builtin_amdgcn_global_load_lds((const __attribute__((address_space(1))) void*)(gp), \
                                   (__attribute__((address_space(3))) void*)(lp), 16, 0, 0)

// ---------------- W fp32 -> bf16 ----------------
__global__ __launch_bounds__(256) void k_wcvt(const float* __restrict__ wqkv,
                                              const float* __restrict__ wout,
                                              us16* __restrict__ wbf) {
  int i = (blockIdx.x * 256 + threadIdx.x) * 4;
  const float* s = (i < 442368) ? (wqkv + i) : (wout + (i - 442368));
  wbf[i + 0] = f2bfu(s[0]); wbf[i + 1] = f2bfu(s[1]);
  wbf[i + 2] = f2bfu(s[2]); wbf[i + 3] = f2bfu(s[3]);
}

// ---------------- K1: prenorm ----------------
__global__ __launch_bounds__(256) void k_prenorm(const float* __restrict__ x,
                                                 const float* __restrict__ g,
                                                 us16* __restrict__ xn) {
  __shared__ float gs[384];
  __shared__ float sm[4][64], sq[4][64];
  int t = threadIdx.x;
  for (int c = t; c < 384; c += 256) gs[c] = g[c];
  int qd = t >> 6, pb = t & 63;
  int p = blockIdx.x * 64 + pb;
  int b = p >> 12, pix = p & 4095;
  const float* xb = x + (size_t)b * 1572864 + pix;
  float xv[96];
  float s1 = 0.f, s2 = 0.f;
  #pragma unroll
  for (int i = 0; i < 96; ++i) {
    float v = xb[(size_t)(qd * 96 + i) * 4096];
    xv[i] = v; s1 += v; s2 += v * v;
  }
  sm[qd][pb] = s1; sq[qd][pb] = s2;
  __syncthreads();
  float su = sm[0][pb] + sm[1][pb] + sm[2][pb] + sm[3][pb];
  float ss = sq[0][pb] + sq[1][pb] + sq[2][pb] + sq[3][pb];
  float mean = su * (1.f / 384);
  float var = ss * (1.f / 384) - mean * mean;
  float rs = rsqrtf(var + EPS_);
  us16* ob = xn + (size_t)p * ROW_ + qd * 96;
  #pragma unroll
  for (int c8 = 0; c8 < 12; ++c8) {
    ushort8 u;
    #pragma unroll
    for (int j = 0; j < 8; ++j)
      u[j] = f2bfu((xv[c8 * 8 + j] - mean) * rs * gs[qd * 96 + c8 * 8 + j]);
    *(ushort8*)(ob + c8 * 8) = u;
  }
}

// ---------------- MFMA GEMM: dst[p][o] = sum_c src[p][c] * W[o][c] --------
// mode 0 (QKV): q -> [h][P][96]; k -> exp(k) transposed [4+h][96][P];
//               v -> transposed [8+h][96][P]
// mode 1 (Wout): y [P][384]
__global__ __launch_bounds__(256) void k_gemm(const us16* __restrict__ src,
                                              const us16* __restrict__ W,
                                              us16* __restrict__ dst,
                                              int MT, int mode) {
  __shared__ __align__(16) us16 As[128 * 32];
  __shared__ __align__(16) us16 Bs[128 * 32];
  int i = blockIdx.x;
  int xcd = i & 7, idx = i >> 3;
  int ot = idx % MT;
  int pt = (idx / MT) * 8 + xcd;
  int p0 = pt * 128, o0 = ot * 128;
  int tid = threadIdx.x;
  int wv = tid >> 6, l = tid & 63;
  int wr = wv >> 1, wc = wv & 1;
  int lm = l & 15, kq = l >> 4;

  f32x4 acc[4][4];
  #pragma unroll
  for (int a = 0; a < 4; ++a)
    #pragma unroll
    for (int q = 0; q < 4; ++q) acc[a][q] = (f32x4)0.f;

  int lrow = l >> 2, lcol = (l & 3) * 8;

  for (int k0 = 0; k0 < 384; k0 += 32) {
    #pragma unroll
    for (int c = 0; c < 2; ++c) {
      int ra = wv * 32 + c * 16;
      GLDS16(src + (size_t)(p0 + ra + lrow) * ROW_ + k0 + lcol, &As[ra * 32]);
      GLDS16(W   + (size_t)(o0 + ra + lrow) * ROW_ + k0 + lcol, &Bs[ra * 32]);
    }
    __syncthreads();
    const short8* A8 = (const short8*)As;
    const short8* B8 = (const short8*)Bs;
    short8 af[4], bf[4];
    #pragma unroll
    for (int ii = 0; ii < 4; ++ii) af[ii] = A8[(wr * 64 + ii * 16 + lm) * 4 + kq];
    #pragma unroll
    for (int jj = 0; jj < 4; ++jj) bf[jj] = B8[(wc * 64 + jj * 16 + lm) * 4 + kq];
    #pragma unroll
    for (int ii = 0; ii < 4; ++ii)
      #pragma unroll
      for (int jj = 0; jj < 4; ++jj)
        acc[ii][jj] = __builtin_amdgcn_mfma_f32_16x16x32_bf16(af[ii], bf[jj], acc[ii][jj], 0, 0, 0);
    __syncthreads();
  }

  // C/D layout: col=o=lane&15, row=p=(lane>>4)*4+reg (m89/m91-verified)
  #pragma unroll
  for (int ii = 0; ii < 4; ++ii) {
    int prow = p0 + wr * 64 + ii * 16 + kq * 4;
    #pragma unroll
    for (int jj = 0; jj < 4; ++jj) {
      int o = o0 + wc * 64 + jj * 16 + lm;
      f32x4 v = acc[ii][jj];
      if (mode) {
        #pragma unroll
        for (int r = 0; r < 4; ++r)
          dst[(size_t)(prow + r) * ROW_ + o] = f2bfu(v[r]);
      } else {
        int sec = o / 96, d = o % 96;     // wave-uniform sec (96 % 16 == 0 tiles)
        if (sec < 4) {
          #pragma unroll
          for (int r = 0; r < 4; ++r)
            dst[(size_t)sec * P96_ + (size_t)(prow + r) * 96 + d] = f2bfu(v[r]);
        } else {
          bool isk = sec < 8;
          alignas(8) us16 buf[4];
          #pragma unroll
          for (int r = 0; r < 4; ++r) {
            float f = v[r];
            if (isk) f = __expf(f);
            buf[r] = f2bfu(f);
          }
          *(uint2*)(dst + (size_t)sec * P96_ + (size_t)d * P_ + prow) = *(const uint2*)buf;
        }
      }
    }
  }
}

// ---------------- K4: MFMA ctx. ctxs[s][bh][d][e] = sum_p ek[d,p] v[e,p] --
// M=96(d) x N=96(e) x K=CHK_(p). 2x2 waves, 3x3 16x16x32 frags.
// Z via all-ones B fragment. XOR-swizzled LDS staging (bank-conflict-free).
__global__ __launch_bounds__(256) void k_ctx(const us16* __restrict__ qkv,
                                             float* __restrict__ ctxs,
                                             float* __restrict__ zs) {
  __shared__ __align__(16) us16 Ek[96 * 64];
  __shared__ __align__(16) us16 Vv[96 * 64];
  int bh = blockIdx.x, s = blockIdx.y;
  int b = bh >> 2, h = bh & 3;
  const us16* kb = qkv + (size_t)(4 + h) * P96_;
  const us16* vb = qkv + (size_t)(8 + h) * P96_;
  int pbase = b * 4096 + s * CHK_;
  int t = threadIdx.x;
  int wv = t >> 6, l = t & 63;
  int wr = wv >> 1, wc = wv & 1;
  int lm = l & 15, kq = l >> 4;

  f32x4 acc[3][3];
  f32x4 accz[3];
  #pragma unroll
  for (int a = 0; a < 3; ++a) {
    accz[a] = (f32x4)0.f;
    #pragma unroll
    for (int q = 0; q < 3; ++q) acc[a][q] = (f32x4)0.f;
  }
  short8 vone;
  #pragma unroll
  for (int j = 0; j < 8; ++j) vone[j] = (short)0x3F80;   // bf16 1.0

  int srow = wv * 24 + (l >> 3);   // staged row (+c*8), 8 rows / instruction
  int sgrp = l & 7;                // 16B group within 128B row

  for (int tile = 0; tile < CHK_ / 64; ++tile) {
    int p0 = pbase + tile * 64;
    #pragma unroll
    for (int c = 0; c < 3; ++c) {
      int r = srow + c * 8;
      int g = sgrp ^ (r & 7);      // XOR swizzle: LDS[r][sgrp] holds global group g
      GLDS16(kb + (size_t)r * P_ + p0 + g * 8, &Ek[(wv * 24 + c * 8) * 64]);
      GLDS16(vb + (size_t)r * P_ + p0 + g * 8, &Vv[(wv * 24 + c * 8) * 64]);
    }
    __syncthreads();
    const short8* A8 = (const short8*)Ek;
    const short8* B8 = (const short8*)Vv;
    #pragma unroll
    for (int ks = 0; ks < 2; ++ks) {
      short8 af[3], bf[3];
      #pragma unroll
      for (int ii = 0; ii < 3; ++ii) {
        int m = wr * 48 + ii * 16 + lm;
        af[ii] = A8[m * 8 + (((ks * 4 + kq) ^ m) & 7) + ((ks * 4 + kq) & 8)];
        int e = wc * 48 + ii * 16 + lm;
        bf[ii] = B8[e * 8 + (((ks * 4 + kq) ^ e) & 7) + ((ks * 4 + kq) & 8)];
      }
      #pragma unroll
      for (int ii = 0; ii < 3; ++ii)
        #pragma unroll
        for (int jj = 0; jj < 3; ++jj)
          acc[ii][jj] = __builtin_amdgcn_mfma_f32_16x16x32_bf16(af[ii], bf[jj], acc[ii][jj], 0, 0, 0);
      if (wc == 0) {
        #pragma unroll
        for (int ii = 0; ii < 3; ++ii)
          accz[ii] = __builtin_amdgcn_mfma_f32_16x16x32_bf16(af[ii], vone, accz[ii], 0, 0, 0);
      }
    }
    __syncthreads();
  }

  float* cb = ctxs + (size_t)(s * 64 + bh) * 9216;
  #pragma unroll
  for (int ii = 0; ii < 3; ++ii) {
    int m0 = wr * 48 + ii * 16 + kq * 4;
    #pragma unroll
    for (int jj = 0; jj < 3; ++jj) {
      int e = wc * 48 + jj * 16 + lm;
      #pragma unroll
      for (int r = 0; r < 4; ++r)
        cb[(size_t)(m0 + r) * 96 + e] = acc[ii][jj][r];
    }
  }
  if (wc == 0 && lm == 0) {
    #pragma unroll
    for (int ii = 0; ii < 3; ++ii) {
      int m0 = wr * 48 + ii * 16 + kq * 4;
      #pragma unroll
      for (int r = 0; r < 4; ++r)
        zs[(size_t)(s * 64 + bh) * 96 + m0 + r] = accz[ii][r];
    }
  }
}

// ---------------- K4b: reduce the NS_ split slices ------------------------
__global__ __launch_bounds__(256) void k_ctxred(const float* __restrict__ ctxs,
                                                const float* __restrict__ zs,
                                                float* __restrict__ ctx,
                                                float* __restrict__ zr) {
  int bh = blockIdx.x / 9, part = blockIdx.x % 9;
  int t = threadIdx.x;
  int idx = part * 1024 + t * 4;
  f32x4 sum = (f32x4)0.f;
  #pragma unroll
  for (int s = 0; s < NS_; ++s)
    sum += *(const f32x4*)&ctxs[(size_t)(s * 64 + bh) * 9216 + idx];
  *(f32x4*)&ctx[(size_t)bh * 9216 + idx] = sum;
  if (part == 0 && t < 96) {
    float z = 0.f;
    #pragma unroll
    for (int s = 0; s < NS_; ++s) z += zs[(size_t)(s * 64 + bh) * 96 + t];
    zr[bh * 96 + t] = z;
  }
}

// ---------------- K5: q-softmax*SCALE/Z, out[p][e] = sum_d qv[d]*ctx[d][e]
__global__ __launch_bounds__(256) void k_attout(const us16* __restrict__ qkv,
                                                const float* __restrict__ ctx,
                                                const float* __restrict__ zr,
                                                us16* __restrict__ attout) {
  __shared__ float cs[9216];
  __shared__ float zrs[96];
  int bh = blockIdx.y, b = bh >> 2, h = bh & 3;
  int t = threadIdx.x;
  const float* cb = ctx + (size_t)bh * 9216;
  for (int i = t; i < 9216; i += 256) cs[i] = cb[i];
  if (t < 96) zrs[t] = 1.0f / zr[bh * 96 + t];
  __syncthreads();
  int p = b * 4096 + blockIdx.x * 256 + t;
  const us16* qrow = qkv + (size_t)h * P96_ + (size_t)p * 96;
  float qv[96];
  #pragma unroll
  for (int c8 = 0; c8 < 12; ++c8) {
    ushort8 u = *(const ushort8*)(qrow + c8 * 8);
    #pragma unroll
    for (int j = 0; j < 8; ++j) qv[c8 * 8 + j] = bfu2f(u[j]);
  }
  float m = -1e30f;
  #pragma unroll
  for (int d = 0; d < 96; ++d) m = fmaxf(m, qv[d]);
  float s = 0.f;
  #pragma unroll
  for (int d = 0; d < 96; ++d) { qv[d] = __expf(qv[d] - m); s += qv[d]; }
  float sc = SCALE_ / s;
  #pragma unroll
  for (int d = 0; d < 96; ++d) qv[d] *= sc * zrs[d];
  us16* ob = attout + (size_t)p * ROW_ + h * 96;
  #pragma unroll 1
  for (int e0 = 0; e0 < 96; e0 += 8) {
    float a0 = 0, a1 = 0, a2 = 0, a3 = 0, a4 = 0, a5 = 0, a6 = 0, a7 = 0;
    #pragma unroll
    for (int d = 0; d < 96; ++d) {
      float qd = qv[d];
      f32x4 c0 = *(const f32x4*)&cs[d * 96 + e0];
      f32x4 c1 = *(const f32x4*)&cs[d * 96 + e0 + 4];
      a0 += qd * c0[0]; a1 += qd * c0[1]; a2 += qd * c0[2]; a3 += qd * c0[3];
      a4 += qd * c1[0]; a5 += qd * c1[1]; a6 += qd * c1[2]; a7 += qd * c1[3];
    }
    ushort8 u;
    u[0] = f2bfu(a0); u[1] = f2bfu(a1); u[2] = f2bfu(a2); u[3] = f2bfu(a3);
    u[4] = f2bfu(a4); u[5] = f2bfu(a5); u[6] = f2bfu(a6); u[7] = f2bfu(a7);
    *(ushort8*)(ob + e0) = u;
  }
}

// ---------------- K7: +bias, channel LN, *g, +xn, write channel-major fp32
__global__ __launch_bounds__(256) void k_outnorm(const us16* __restrict__ y,
                                                 const us16* __restrict__ xn,
                                                 const float* __restrict__ bout,
                                                 const float* __restrict__ g,
                                                 float* __restrict__ out) {
  __shared__ float bs[384], gs[384];
  int t = threadIdx.x;
  for (int c = t; c < 384; c += 256) { bs[c] = bout[c]; gs[c] = g[c]; }
  __syncthreads();
  int p = blockIdx.x * 256 + t;
  int b = p >> 12, pix = p & 4095;
  const us16* yb = y + (size_t)p * ROW_;
  const us16* xb = xn + (size_t)p * ROW_;
  float sum = 0.f, sq = 0.f;
  #pragma unroll 4
  for (int c8 = 0; c8 < 48; ++c8) {
    ushort8 u = *(const ushort8*)(yb + c8 * 8);
    #pragma unroll
    for (int j = 0; j < 8; ++j) {
      float v = bfu2f(u[j]) + bs[c8 * 8 + j];
      sum += v; sq += v * v;
    }
  }
  float mean = sum * (1.f / 384);
  float var = sq * (1.f / 384) - mean * mean;
  float rs = rsqrtf(var + EPS_);
  float* oB = out + (size_t)b * 1572864 + pix;
  #pragma unroll 2
  for (int c8 = 0; c8 < 48; ++c8) {
    ushort8 u = *(const ushort8*)(yb + c8 * 8);
    ushort8 ux = *(const ushort8*)(xb + c8 * 8);
    #pragma unroll
    for (int j = 0; j < 8; ++j) {
      int c = c8 * 8 + j;
      float v = bfu2f(u[j]) + bs[c];
      oB[(size_t)c * 4096] = (v - mean) * rs * gs[c] + bfu2f(ux[j]);
    }
  }
}

extern "C" void kernel_launch(void* const* d_in, const int* in_sizes, int n_in,
                              void* d_out, int out_size, void* d_ws, size_t ws_size,
                              hipStream_t stream) {
  const float* x    = (const float*)d_in[0];
  const float* pg   = (const float*)d_in[1];
  const float* wqkv = (const float*)d_in[2];
  const float* wout = (const float*)d_in[3];
  const float* bout = (const float*)d_in[4];
  const float* og   = (const float*)d_in[5];

  char* ws = (char*)d_ws;
  us16*  xn     = (us16*)(ws);
  us16*  qkv    = (us16*)(ws + 50331648);
  us16*  attout = (us16*)(ws + 201326592);
  float* ctxred = (float*)(ws + 251658240);
  float* zred   = (float*)(ws + 254017536);
  us16*  wbf    = (us16*)(ws + 254042112);
  us16*  y      = qkv;                          // q section reused after K5
  float* out    = (float*)d_out;
  // d_out as pre-epilogue scratch (dead until k_outnorm):
  float* ctxs = (float*)d_out;                  // 8*64*9216*4 = 18,874,368 B
  float* zs   = (float*)((char*)d_out + 18874368);  // 8*64*96*4 = 196,608 B

  k_wcvt<<<576, 256, 0, stream>>>(wqkv, wout, wbf);
  k_prenorm<<<1024, 256, 0, stream>>>(x, pg, xn);
  k_gemm<<<4608, 256, 0, stream>>>(xn, wbf, qkv, 9, 0);
  k_ctx<<<dim3(64, NS_), 256, 0, stream>>>(qkv, ctxs, zs);
  k_ctxred<<<576, 256, 0, stream>>>(ctxs, zs, ctxred, zred);
  k_attout<<<dim3(16, 64), 256, 0, stream>>>(qkv, ctxred, zred, attout);
  k_gemm<<<1536, 256, 0, stream>>>(attout, wbf + 442368, y, 3, 1);
  k_outnorm<<<256, 256, 0, stream>>>(y, xn, bout, og, out);
}